// Round 1
// baseline (2335.112 us; speedup 1.0000x reference)
//
#include <hip/hip_runtime.h>
#include <hip/hip_bf16.h>
#include <math.h>

#define NT 256   // threads per block (4 waves)
#define EB 16    // edges per block

// LDS: 59,648 bytes total (< 64 KB) -> 2 blocks/CU
struct SM {
  __hip_bfloat16 m0[EB][464];   // [s0(64)|s1c1(32)|s2c2(16)] x3 segs | lat(128)
  __hip_bfloat16 p1[EB][144];   // [s1c2(32)|s2c3(16)] x3
  __hip_bfloat16 n1[EB][144];   // [s1c0(32)|s2c1(16)] x3
  __hip_bfloat16 p2[EB][48];    // s2c4 x3
  __hip_bfloat16 n2[EB][48];    // s2c0 x3
  float o0[EB][160];
  float op1[EB][48];
  float on1[EB][48];
  float op2[EB][16];
  float on2[EB][16];
  float wtile[2560];            // weight staging; aliased as epilogue scratch (4 waves x 288)
  float scr[4][240];            // per-wave LN'd row scratch (phase 1)
};

__device__ __forceinline__ float wred(float v) {
  #pragma unroll
  for (int s = 32; s > 0; s >>= 1) v += __shfl_xor(v, s, 64);
  return v;
}

__global__ __launch_bounds__(NT, 2)
void iel_fused(const float* __restrict__ latents,
               const float* __restrict__ nodef,
               const float* __restrict__ edgef,
               const float* __restrict__ wig,
               const float* __restrict__ ln_n_w0, const float* __restrict__ ln_n_b0,
               const float* __restrict__ ln_n_w1, const float* __restrict__ ln_n_w2,
               const float* __restrict__ ln_e_w0, const float* __restrict__ ln_e_b0,
               const float* __restrict__ ln_e_w1, const float* __restrict__ ln_e_w2,
               const float* __restrict__ so2_w0,
               const float* __restrict__ so2_w1r, const float* __restrict__ so2_w1i,
               const float* __restrict__ so2_w2r, const float* __restrict__ so2_w2i,
               const float* __restrict__ lp_w0, const float* __restrict__ lp_b0,
               const float* __restrict__ lp_w1, const float* __restrict__ lp_w2,
               const int* __restrict__ edge_index, const int* __restrict__ active_edges,
               float* __restrict__ out,
               int Etot, int A)
{
  __shared__ SM sm;
  const int t    = threadIdx.x;
  const int lane = t & 63;
  const int w    = t >> 6;
  const int eb0  = blockIdx.x * EB;

  // ---------------- Phase 1: LN + forward rotation -> LDS feature matrices ----
  for (int it = 0; it < 4; ++it) {
    const int el = w * 4 + it;
    const int e  = eb0 + el;
    const bool valid = (e < A);
    int ae = 0, ec = 0, en = 0;
    if (valid) {
      ae = active_edges[e];
      ec = edge_index[ae];
      en = edge_index[Etot + ae];
    }
    const float* Drow = wig + (size_t)e * 81;
    const float  D00  = valid ? Drow[0] : 0.f;

    for (int r = 0; r < 3; ++r) {
      const float *src, *w0, *b0, *w1, *w2;
      if (r == 0)      { src = nodef + (size_t)ec * 240; w0 = ln_n_w0; b0 = ln_n_b0; w1 = ln_n_w1; w2 = ln_n_w2; }
      else if (r == 1) { src = edgef + (size_t)e  * 240; w0 = ln_e_w0; b0 = ln_e_b0; w1 = ln_e_w1; w2 = ln_e_w2; }
      else             { src = nodef + (size_t)en * 240; w0 = ln_n_w0; b0 = ln_n_b0; w1 = ln_n_w1; w2 = ln_n_w2; }

      float v0 = 0.f, v1 = 0.f, v2 = 0.f, v3 = 0.f;
      if (valid) {
        v0 = src[lane];
        v1 = src[lane + 64];
        v2 = src[lane + 128];
        v3 = (lane < 48) ? src[lane + 192] : 0.f;
      }
      const float mu   = wred(v0) * (1.f / 64.f);
      const float c0   = v0 - mu;
      const float var0 = wred(c0 * c0) * (1.f / 64.f);
      const float s1p  = v1 * v1 + ((lane < 32) ? v2 * v2 : 0.f);
      const float s2p  = ((lane >= 32) ? v2 * v2 : 0.f) + v3 * v3;
      const float S1   = wred(s1p);
      const float S2   = wred(s2p);
      const float inv  = rsqrtf(0.5f * (S1 * (1.f / 96.f) + S2 * (1.f / 80.f)) + 1e-8f);
      const float i0   = rsqrtf(var0 + 1e-8f);

      float* scr = sm.scr[w];
      scr[lane] = c0 * i0 * w0[lane] + b0[lane];
      { int o = lane + 64;  int c = (o - 64) / 3;  scr[o] = v1 * inv * w1[c]; }
      { int o = lane + 128; float y;
        if (o < 160) { int c = (o - 64) / 3;  y = v2 * inv * w1[c]; }
        else         { int c = (o - 160) / 5; y = v2 * inv * w2[c]; }
        scr[o] = y; }
      if (lane < 48) { int o = lane + 192; int c = (o - 160) / 5; scr[o] = v3 * inv * w2[c]; }
      __syncthreads();

      if (valid) {
        #pragma unroll
        for (int q = 0; q < 4; ++q) {
          const int o = lane + 64 * q;
          if (o >= 240) break;
          if (o < 64) {
            sm.m0[el][r * 112 + o] = __float2bfloat16(scr[o] * D00);
          } else if (o < 160) {
            const int u = o - 64, c = u / 3, i = u % 3;
            const float* db = Drow + (1 + i) * 9 + 1;
            const float* s  = scr + 64 + c * 3;
            const float val = db[0] * s[0] + db[1] * s[1] + db[2] * s[2];
            const __hip_bfloat16 bv = __float2bfloat16(val);
            if (i == 1)      sm.m0[el][r * 112 + 64 + c] = bv;
            else if (i == 2) sm.p1[el][r * 48 + c]       = bv;
            else             sm.n1[el][r * 48 + c]       = bv;
          } else {
            const int u = o - 160, c = u / 5, i = u % 5;
            const float* db = Drow + (4 + i) * 9 + 4;
            const float* s  = scr + 160 + c * 5;
            const float val = db[0]*s[0] + db[1]*s[1] + db[2]*s[2] + db[3]*s[3] + db[4]*s[4];
            const __hip_bfloat16 bv = __float2bfloat16(val);
            if (i == 2)      sm.m0[el][r * 112 + 96 + c] = bv;
            else if (i == 3) sm.p1[el][r * 48 + 32 + c]  = bv;
            else if (i == 1) sm.n1[el][r * 48 + 32 + c]  = bv;
            else if (i == 4) sm.p2[el][r * 16 + c]       = bv;
            else             sm.n2[el][r * 16 + c]       = bv;
          }
        }
      }
      __syncthreads();
    }
    if (valid) {
      const float* lrow = latents + (size_t)ae * 128;
      sm.m0[el][336 + lane]      = __float2bfloat16(lrow[lane]);
      sm.m0[el][336 + 64 + lane] = __float2bfloat16(lrow[64 + lane]);
    }
  }
  __syncthreads();

  // ---------------- Phase 2a: o0 = m0 @ so2_w0 * inv_sqrt(464) ----------------
  {
    const int eg = t >> 5;        // 8 groups x 2 edges
    const int cg = t & 31;        // 32 groups x 5 cols
    const int e0 = eg * 2;
    float acc0[5] = {0,0,0,0,0}, acc1[5] = {0,0,0,0,0};
    for (int kb = 0; kb < 29; ++kb) {
      #pragma unroll
      for (int u = 0; u < 10; ++u) {
        const int idx = t + NT * u;
        sm.wtile[idx] = so2_w0[kb * 16 * 160 + idx];
      }
      __syncthreads();
      for (int kk = 0; kk < 16; ++kk) {
        const int k = kb * 16 + kk;
        const float a0 = __bfloat162float(sm.m0[e0][k]);
        const float a1 = __bfloat162float(sm.m0[e0 + 1][k]);
        const float* wr = &sm.wtile[kk * 160 + cg * 5];
        #pragma unroll
        for (int u = 0; u < 5; ++u) {
          const float wv = wr[u];
          acc0[u] += a0 * wv;
          acc1[u] += a1 * wv;
        }
      }
      __syncthreads();
    }
    const float s = 1.f / sqrtf(464.f);
    #pragma unroll
    for (int u = 0; u < 5; ++u) {
      sm.o0[e0][cg * 5 + u]     = acc0[u] * s;
      sm.o0[e0 + 1][cg * 5 + u] = acc1[u] * s;
    }
  }
  __syncthreads();

  // ---------------- Phase 2b: op1/on1 = complex(p1,n1) @ (w1r,w1i) / 12 -------
  {
    const int e  = t >> 4;          // 16 edges
    const int cb = (t & 15) * 3;    // 16 groups x 3 cols
    float ap[3] = {0,0,0}, an[3] = {0,0,0};
    for (int kb = 0; kb < 9; ++kb) {
      #pragma unroll
      for (int u = 0; u < 3; ++u) {
        const int idx = t + NT * u;   // 768 per matrix
        sm.wtile[idx]       = so2_w1r[kb * 16 * 48 + idx];
        sm.wtile[768 + idx] = so2_w1i[kb * 16 * 48 + idx];
      }
      __syncthreads();
      for (int kk = 0; kk < 16; ++kk) {
        const int k = kb * 16 + kk;
        const float p = __bfloat162float(sm.p1[e][k]);
        const float n = __bfloat162float(sm.n1[e][k]);
        const float* wr = &sm.wtile[kk * 48 + cb];
        const float* wi = &sm.wtile[768 + kk * 48 + cb];
        #pragma unroll
        for (int u = 0; u < 3; ++u) {
          ap[u] += p * wr[u] - n * wi[u];
          an[u] += p * wi[u] + n * wr[u];
        }
      }
      __syncthreads();
    }
    const float s = 1.f / 12.f;
    #pragma unroll
    for (int u = 0; u < 3; ++u) {
      sm.op1[e][cb + u] = ap[u] * s;
      sm.on1[e][cb + u] = an[u] * s;
    }
  }
  __syncthreads();

  // ---------------- Phase 2c: op2/on2 = complex(p2,n2) @ (w2r,w2i) /sqrt(48) --
  {
    #pragma unroll
    for (int u = 0; u < 3; ++u) {
      const int idx = t + NT * u;     // 768 per matrix
      sm.wtile[idx]       = so2_w2r[idx];
      sm.wtile[768 + idx] = so2_w2i[idx];
    }
    __syncthreads();
    const int e = t >> 4;
    const int c = t & 15;
    float ap = 0.f, an = 0.f;
    for (int k = 0; k < 48; ++k) {
      const float p  = __bfloat162float(sm.p2[e][k]);
      const float n  = __bfloat162float(sm.n2[e][k]);
      const float wr = sm.wtile[k * 16 + c];
      const float wi = sm.wtile[768 + k * 16 + c];
      ap += p * wr - n * wi;
      an += p * wi + n * wr;
    }
    const float s = 1.f / sqrtf(48.f);
    sm.op2[e][c] = ap * s;
    sm.on2[e][c] = an * s;
  }
  __syncthreads();

  // ---------------- Phase 3: rotate-back, gates, final matmuls, store ---------
  float* esc = sm.wtile + w * 288;   // per-wave: sc(64) | gates(48) | g1(96) | g2(80)
  for (int it = 0; it < 4; ++it) {
    const int el = w * 4 + it;
    const int e  = eb0 + el;
    const bool valid = (e < A);
    const float* Drow = wig + (size_t)e * 81;
    const float  D00  = valid ? Drow[0] : 0.f;

    if (valid) {
      const float x = sm.o0[el][lane] * D00;
      esc[lane] = x / (1.f + expf(-x));                 // silu
      if (lane < 48) {
        const float g = sm.o0[el][64 + lane] * D00;
        esc[64 + lane] = 1.f / (1.f + expf(-g));        // gate
      }
    }
    __syncthreads();

    if (valid) {
      #pragma unroll
      for (int q = 0; q < 3; ++q) {
        const int idx = lane + 64 * q;
        if (idx < 96) {
          const int c = idx / 3, m = idx % 3;
          const float j0 = sm.on1[el][c];
          const float j1 = sm.o0[el][112 + c];
          const float j2 = sm.op1[el][c];
          const float val = Drow[1*9 + 1 + m] * j0 + Drow[2*9 + 1 + m] * j1 + Drow[3*9 + 1 + m] * j2;
          esc[112 + idx] = val * esc[64 + c];
        } else if (idx < 176) {
          const int u = idx - 96, c = u / 5, m = u % 5;
          const float j0 = sm.on2[el][c];
          const float j1 = sm.on1[el][32 + c];
          const float j2 = sm.o0[el][144 + c];
          const float j3 = sm.op1[el][32 + c];
          const float j4 = sm.op2[el][c];
          const float val = Drow[4*9 + 4 + m] * j0 + Drow[5*9 + 4 + m] * j1 + Drow[6*9 + 4 + m] * j2
                          + Drow[7*9 + 4 + m] * j3 + Drow[8*9 + 4 + m] * j4;
          esc[112 + idx] = val * esc[96 + c];
        }
      }
    }
    __syncthreads();

    if (valid) {
      float* orow = out + (size_t)e * 240;
      #pragma unroll
      for (int q = 0; q < 4; ++q) {
        const int o = lane + 64 * q;
        if (o >= 240) break;
        float y;
        if (o < 64) {
          float acc = 0.f;
          #pragma unroll
          for (int c = 0; c < 64; ++c) acc += esc[c] * lp_w0[c * 64 + o];
          y = acc * 0.125f + lp_b0[o];
        } else if (o < 160) {
          const int d = (o - 64) / 3, m = (o - 64) % 3;
          float acc = 0.f;
          #pragma unroll
          for (int c = 0; c < 32; ++c) acc += esc[112 + c * 3 + m] * lp_w1[c * 32 + d];
          y = acc * (1.f / sqrtf(32.f));
        } else {
          const int d = (o - 160) / 5, m = (o - 160) % 5;
          float acc = 0.f;
          #pragma unroll
          for (int c = 0; c < 16; ++c) acc += esc[208 + c * 5 + m] * lp_w2[c * 16 + d];
          y = acc * 0.25f;
        }
        orow[o] = y;
      }
    }
    __syncthreads();
  }
}

extern "C" void kernel_launch(void* const* d_in, const int* in_sizes, int n_in,
                              void* d_out, int out_size, void* d_ws, size_t ws_size,
                              hipStream_t stream) {
  const float* latents  = (const float*)d_in[0];
  const float* nodef    = (const float*)d_in[1];
  const float* edgef    = (const float*)d_in[2];
  // d_in[3] = edge_vector (unused by reference forward)
  const float* wig      = (const float*)d_in[4];
  const float* ln_n_w0  = (const float*)d_in[5];
  const float* ln_n_b0  = (const float*)d_in[6];
  const float* ln_n_w1  = (const float*)d_in[7];
  const float* ln_n_w2  = (const float*)d_in[8];
  const float* ln_e_w0  = (const float*)d_in[9];
  const float* ln_e_b0  = (const float*)d_in[10];
  const float* ln_e_w1  = (const float*)d_in[11];
  const float* ln_e_w2  = (const float*)d_in[12];
  const float* so2_w0   = (const float*)d_in[13];
  const float* so2_w1r  = (const float*)d_in[14];
  const float* so2_w1i  = (const float*)d_in[15];
  const float* so2_w2r  = (const float*)d_in[16];
  const float* so2_w2i  = (const float*)d_in[17];
  const float* lp_w0    = (const float*)d_in[18];
  const float* lp_b0    = (const float*)d_in[19];
  const float* lp_w1    = (const float*)d_in[20];
  const float* lp_w2    = (const float*)d_in[21];
  const int*   edge_index   = (const int*)d_in[22];
  const int*   active_edges = (const int*)d_in[23];

  const int Etot = in_sizes[2] / 240;   // edge_features rows
  const int A    = in_sizes[23];        // number of active edges (output rows)
  const int grid = (A + EB - 1) / EB;

  hipLaunchKernelGGL(iel_fused, dim3(grid), dim3(NT), 0, stream,
                     latents, nodef, edgef, wig,
                     ln_n_w0, ln_n_b0, ln_n_w1, ln_n_w2,
                     ln_e_w0, ln_e_b0, ln_e_w1, ln_e_w2,
                     so2_w0, so2_w1r, so2_w1i, so2_w2r, so2_w2i,
                     lp_w0, lp_b0, lp_w1, lp_w2,
                     edge_index, active_edges,
                     (float*)d_out, Etot, A);
}

// Round 3
// 1192.563 us; speedup vs baseline: 1.9581x; 1.9581x over previous
//
#include <hip/hip_runtime.h>
#include <hip/hip_bf16.h>
#include <math.h>

#define NT 256   // 4 waves
#define EB 32    // edges per block

using short8 = __attribute__((ext_vector_type(8))) short;
using f32x4  = __attribute__((ext_vector_type(4))) float;
typedef unsigned short u16;

#define MFMA(a,b,c) __builtin_amdgcn_mfma_f32_16x16x32_bf16((a),(b),(c),0,0,0)

// ---- swizzled-weight fragment table indices (each frag = 64 lanes x 8 bf16 = 1024B)
#define FW0   0     // so2_w0: K=464->480 (15 kt) x N=160 (10 nt) = 150 frags
#define FW1R  150   // w1r: K=144->160 (5) x N=48 (3) = 15
#define FW1I  165
#define FW1IN 180   // -w1i
#define FW2R  195   // w2r: K=48->64 (2) x N=16 (1) = 2
#define FW2I  197
#define FW2IN 199
#define FL0   201   // lp_w0: K=64 (2) x N=64 (4) = 8
#define FL1   209   // lp_w1: K=32 (1) x N=32 (2) = 2
#define FL2   211   // lp_w2: K=16->32 (1) x N=16 (1) = 1
#define NFRAG 212

__device__ __forceinline__ u16 f2b(float x) {
  __hip_bfloat16 h = __float2bfloat16(x);
  return *reinterpret_cast<u16*>(&h);
}
__device__ __forceinline__ float b2f(u16 u) {
  __hip_bfloat16 h; *reinterpret_cast<u16*>(&h) = u;
  return __bfloat162float(h);
}
__device__ __forceinline__ float wred(float v) {
  #pragma unroll
  for (int s = 32; s > 0; s >>= 1) v += __shfl_xor(v, s, 64);
  return v;
}

// ---------------- weight pre-swizzle: f32 [K][N] -> bf16 B-fragments ----------
__global__ void prep_w(const float* __restrict__ w0,
                       const float* __restrict__ w1r, const float* __restrict__ w1i,
                       const float* __restrict__ w2r, const float* __restrict__ w2i,
                       const float* __restrict__ l0,  const float* __restrict__ l1,
                       const float* __restrict__ l2,  u16* __restrict__ ws) {
  const int g = blockIdx.x * 256 + threadIdx.x;
  if (g >= NFRAG * 64) return;
  const int frag = g >> 6, lane = g & 63;
  const float* src; int K, N, kt, nt; float sgn = 1.f;
  if (frag < FW1R)       { src = w0;  K = 464; N = 160; int f = frag;       kt = f/10; nt = f%10; }
  else if (frag < FW1I)  { src = w1r; K = 144; N = 48;  int f = frag-FW1R;  kt = f/3;  nt = f%3; }
  else if (frag < FW1IN) { src = w1i; K = 144; N = 48;  int f = frag-FW1I;  kt = f/3;  nt = f%3; }
  else if (frag < FW2R)  { src = w1i; K = 144; N = 48;  int f = frag-FW1IN; kt = f/3;  nt = f%3; sgn = -1.f; }
  else if (frag < FW2I)  { src = w2r; K = 48;  N = 16;  kt = frag-FW2R; nt = 0; }
  else if (frag < FW2IN) { src = w2i; K = 48;  N = 16;  kt = frag-FW2I; nt = 0; }
  else if (frag < FL0)   { src = w2i; K = 48;  N = 16;  kt = frag-FW2IN; nt = 0; sgn = -1.f; }
  else if (frag < FL1)   { src = l0;  K = 64;  N = 64;  int f = frag-FL0;   kt = f/4;  nt = f%4; }
  else if (frag < FL2)   { src = l1;  K = 32;  N = 32;  kt = 0; nt = frag-FL1; }
  else                   { src = l2;  K = 16;  N = 16;  kt = 0; nt = 0; }
  const int n  = nt*16 + (lane & 15);
  const int k0 = kt*32 + (lane >> 4) * 8;
  u16* dst = ws + (size_t)frag * 512 + lane * 8;
  #pragma unroll
  for (int j = 0; j < 8; ++j) {
    const int k = k0 + j;
    const float v = (k < K && n < N) ? src[k * N + n] * sgn : 0.f;
    dst[j] = f2b(v);
  }
}

// ------------------------------ main fused kernel -----------------------------
__global__ __launch_bounds__(NT, 2)
void iel_mfma(const float* __restrict__ latents,
              const float* __restrict__ nodef,
              const float* __restrict__ edgef,
              const float* __restrict__ wig,
              const float* __restrict__ ln_n_w0, const float* __restrict__ ln_n_b0,
              const float* __restrict__ ln_n_w1, const float* __restrict__ ln_n_w2,
              const float* __restrict__ ln_e_w0, const float* __restrict__ ln_e_b0,
              const float* __restrict__ ln_e_w1, const float* __restrict__ ln_e_w2,
              const float* __restrict__ lp_b0,
              const int* __restrict__ edge_index, const int* __restrict__ active_edges,
              const u16* __restrict__ ws,
              float* __restrict__ out,
              int Etot, int A)
{
  __shared__ __align__(16) char SMEM[63488];
  // feature regions (bf16)
  u16*   m0  = (u16*)(SMEM + 0);       // [32][480]
  u16*   p1  = (u16*)(SMEM + 30720);   // [32][160] (K pad 144->160)
  u16*   n1  = (u16*)(SMEM + 40960);   // [32][160]
  u16*   p2  = (u16*)(SMEM + 51200);   // [32][64]  (K pad 48->64)
  u16*   n2  = (u16*)(SMEM + 55296);   // [32][64]
  // phase-2 outputs (aliases, live after the producing barrier)
  float* o0  = (float*)(SMEM + 0);     // [32][160]  (in m0)
  u16*   g2s = (u16*)(SMEM + 20480);   // [5][32][32] (m0 tail)
  float* op1 = (float*)(SMEM + 30720); // [32][48]
  float* on1 = (float*)(SMEM + 36864); // [32][48]
  u16*   scs = (u16*)(SMEM + 43008);   // [32][64]
  u16*   g1s = (u16*)(SMEM + 47104);   // [2][32][32] (m=0,1)
  float* op2 = (float*)(SMEM + 51200); // [32][16]
  float* on2 = (float*)(SMEM + 53248); // [32][16]
  u16*   g1m2= (u16*)(SMEM + 55296);   // [32][32]
  float* scr = (float*)(SMEM + 59392); // [4][240] phase-1 scratch
  u16*   gates=(u16*)(SMEM + 59392);   // [32][48] (aliases scr, post-P1)
  float* d00f= (float*)(SMEM + 63232); // [32]

  const short8* WF = (const short8*)ws;
  const int t    = threadIdx.x;
  const int lane = t & 63;
  const int w    = t >> 6;
  const int eb0  = blockIdx.x * EB;
  const f32x4 ZERO4 = {0.f, 0.f, 0.f, 0.f};

  // ---- pre-clear K-pad columns (zero for MFMA) ----
  for (int i = t; i < 512; i += NT) {
    const int r = i >> 4, c = i & 15;
    m0[r*480 + 464 + c] = 0;
    p1[r*160 + 144 + c] = 0;
    n1[r*160 + 144 + c] = 0;
    p2[r*64  + 48  + c] = 0;
    n2[r*64  + 48  + c] = 0;
  }

  // ---------------- Phase 1: LN + forward rotation (wave-local) ----------------
  float* swr = scr + w * 240;
  for (int it = 0; it < 8; ++it) {
    const int el = w * 8 + it;
    const int e  = eb0 + el;
    const bool valid = (e < A);
    int ae = 0, ec = 0, en = 0;
    if (valid) {
      ae = active_edges[e];
      ec = edge_index[ae];
      en = edge_index[Etot + ae];
    }
    const float* Drow = wig + (size_t)e * 81;
    const float  D00  = valid ? Drow[0] : 0.f;
    if (lane == 0) d00f[el] = D00;

    for (int r = 0; r < 3; ++r) {
      const float *src, *w0, *b0, *w1, *w2;
      if (r == 0)      { src = nodef + (size_t)ec * 240; w0 = ln_n_w0; b0 = ln_n_b0; w1 = ln_n_w1; w2 = ln_n_w2; }
      else if (r == 1) { src = edgef + (size_t)e  * 240; w0 = ln_e_w0; b0 = ln_e_b0; w1 = ln_e_w1; w2 = ln_e_w2; }
      else             { src = nodef + (size_t)en * 240; w0 = ln_n_w0; b0 = ln_n_b0; w1 = ln_n_w1; w2 = ln_n_w2; }

      float v0 = 0.f, v1 = 0.f, v2 = 0.f, v3 = 0.f;
      if (valid) {
        v0 = src[lane];
        v1 = src[lane + 64];
        v2 = src[lane + 128];
        v3 = (lane < 48) ? src[lane + 192] : 0.f;
      }
      const float mu   = wred(v0) * (1.f / 64.f);
      const float c0   = v0 - mu;
      const float var0 = wred(c0 * c0) * (1.f / 64.f);
      const float s1p  = v1 * v1 + ((lane < 32) ? v2 * v2 : 0.f);
      const float s2p  = ((lane >= 32) ? v2 * v2 : 0.f) + v3 * v3;
      const float S1   = wred(s1p);
      const float S2   = wred(s2p);
      const float inv  = rsqrtf(0.5f * (S1 * (1.f / 96.f) + S2 * (1.f / 80.f)) + 1e-8f);
      const float i0   = rsqrtf(var0 + 1e-8f);

      swr[lane] = c0 * i0 * w0[lane] + b0[lane];
      { const int o = lane + 64;  const int c = (o - 64) / 3;  swr[o] = v1 * inv * w1[c]; }
      { const int o = lane + 128; float y;
        if (o < 160) { const int c = (o - 64) / 3;  y = v2 * inv * w1[c]; }
        else         { const int c = (o - 160) / 5; y = v2 * inv * w2[c]; }
        swr[o] = y; }
      if (lane < 48) { const int o = lane + 192; const int c = (o - 160) / 5; swr[o] = v3 * inv * w2[c]; }
      asm volatile("s_waitcnt lgkmcnt(0)" ::: "memory");   // wave-local publish of swr

      if (valid) {
        #pragma unroll
        for (int q = 0; q < 4; ++q) {
          const int o = lane + 64 * q;
          if (o >= 240) break;
          if (o < 64) {
            m0[el*480 + r*112 + o] = f2b(swr[o] * D00);
          } else if (o < 160) {
            const int u = o - 64, c = u / 3, i = u % 3;
            const float* db = Drow + (1 + i) * 9 + 1;
            const float* s  = swr + 64 + c * 3;
            const float val = db[0]*s[0] + db[1]*s[1] + db[2]*s[2];
            const u16 bv = f2b(val);
            if (i == 1)      m0[el*480 + r*112 + 64 + c] = bv;
            else if (i == 2) p1[el*160 + r*48 + c]       = bv;
            else             n1[el*160 + r*48 + c]       = bv;
          } else {
            const int u = o - 160, c = u / 5, i = u % 5;
            const float* db = Drow + (4 + i) * 9 + 4;
            const float* s  = swr + 160 + c * 5;
            const float val = db[0]*s[0] + db[1]*s[1] + db[2]*s[2] + db[3]*s[3] + db[4]*s[4];
            const u16 bv = f2b(val);
            if (i == 2)      m0[el*480 + r*112 + 96 + c] = bv;
            else if (i == 3) p1[el*160 + r*48 + 32 + c]  = bv;
            else if (i == 1) n1[el*160 + r*48 + 32 + c]  = bv;
            else if (i == 4) p2[el*64  + r*16 + c]       = bv;
            else             n2[el*64  + r*16 + c]       = bv;
          }
        }
      }
    }
    if (valid) {
      const float* lrow = latents + (size_t)ae * 128;
      m0[el*480 + 336 + lane]      = f2b(lrow[lane]);
      m0[el*480 + 336 + 64 + lane] = f2b(lrow[64 + lane]);
    }
  }
  __syncthreads();  // B2: features ready

  // ---------------- Phase 2a: o0 = m0 @ so2_w0 (MFMA) -------------------------
  const int mt  = w >> 1;          // wave's M-tile (0/1)
  const int g5  = (w & 1) * 5;     // wave's N-tile group (cols g5*16 .. +80)
  f32x4 acc[5];
  #pragma unroll
  for (int n = 0; n < 5; ++n) acc[n] = ZERO4;
  {
    const u16* abase = m0 + (mt*16 + (lane & 15)) * 480 + (lane >> 4) * 8;
    for (int kt = 0; kt < 15; ++kt) {
      const short8 a = *reinterpret_cast<const short8*>(abase + kt * 32);
      const short8* bp = WF + (size_t)(FW0 + kt*10 + g5) * 64 + lane;
      #pragma unroll
      for (int n = 0; n < 5; ++n)
        acc[n] = MFMA(a, bp[n * 64], acc[n]);
    }
  }
  __syncthreads();  // B3: all waves done reading m0

  // write o0 (aliases m0)
  {
    const float s = 0.046423835f;  // 1/sqrt(464)
    const int col0 = g5*16 + (lane & 15);
    const int r0   = mt*16 + ((lane >> 4) << 2);
    #pragma unroll
    for (int n = 0; n < 5; ++n)
      #pragma unroll
      for (int j = 0; j < 4; ++j)
        o0[(r0 + j)*160 + col0 + n*16] = acc[n][j] * s;
  }

  // ---------------- Phase 2b compute: complex (p1,n1)@(w1r,w1i) ---------------
  f32x4 bacc[3];
  #pragma unroll
  for (int i = 0; i < 3; ++i) bacc[i] = ZERO4;
  #pragma unroll
  for (int i = 0; i < 3; ++i) {
    const int tau = w*3 + i;               // 0..11
    const int isOn = (tau >= 6);
    const int v = isOn ? tau - 6 : tau;
    const int mt2 = v / 3, nt2 = v % 3;
    const u16* pa = p1 + (mt2*16 + (lane & 15)) * 160 + (lane >> 4) * 8;
    const u16* na = n1 + (mt2*16 + (lane & 15)) * 160 + (lane >> 4) * 8;
    const int f1 = isOn ? FW1I  : FW1R;
    const int f2 = isOn ? FW1R  : FW1IN;
    #pragma unroll
    for (int kt = 0; kt < 5; ++kt)
      bacc[i] = MFMA(*reinterpret_cast<const short8*>(pa + kt*32),
                     WF[(size_t)(f1 + kt*3 + nt2) * 64 + lane], bacc[i]);
    #pragma unroll
    for (int kt = 0; kt < 5; ++kt)
      bacc[i] = MFMA(*reinterpret_cast<const short8*>(na + kt*32),
                     WF[(size_t)(f2 + kt*3 + nt2) * 64 + lane], bacc[i]);
  }
  __syncthreads();  // B4: p1/n1 reads done, o0 writes done

  // write op1/on1 (aliases p1 region)
  #pragma unroll
  for (int i = 0; i < 3; ++i) {
    const int tau = w*3 + i;
    const int isOn = (tau >= 6);
    const int v = isOn ? tau - 6 : tau;
    const int mt2 = v / 3, nt2 = v % 3;
    float* dst = isOn ? on1 : op1;
    const int col = nt2*16 + (lane & 15);
    const int r0  = mt2*16 + ((lane >> 4) << 2);
    #pragma unroll
    for (int j = 0; j < 4; ++j)
      dst[(r0 + j)*48 + col] = bacc[i][j] * (1.f / 12.f);
  }

  // ---------------- Phase 2c compute: complex (p2,n2)@(w2r,w2i) ---------------
  f32x4 cacc = ZERO4;
  {
    const int isOn2 = (w >= 2);
    const int mt2 = w & 1;
    const u16* pa = p2 + (mt2*16 + (lane & 15)) * 64 + (lane >> 4) * 8;
    const u16* na = n2 + (mt2*16 + (lane & 15)) * 64 + (lane >> 4) * 8;
    const int f1 = isOn2 ? FW2I : FW2R;
    const int f2 = isOn2 ? FW2R : FW2IN;
    #pragma unroll
    for (int kt = 0; kt < 2; ++kt)
      cacc = MFMA(*reinterpret_cast<const short8*>(pa + kt*32),
                  WF[(size_t)(f1 + kt) * 64 + lane], cacc);
    #pragma unroll
    for (int kt = 0; kt < 2; ++kt)
      cacc = MFMA(*reinterpret_cast<const short8*>(na + kt*32),
                  WF[(size_t)(f2 + kt) * 64 + lane], cacc);
  }
  __syncthreads();  // B5: p2/n2 reads done, op1/on1 writes done

  // write op2/on2 (aliases p2 region)
  {
    float* dst = (w >= 2) ? on2 : op2;
    const int mt2 = w & 1;
    const int col = lane & 15;
    const int r0  = mt2*16 + ((lane >> 4) << 2);
    #pragma unroll
    for (int j = 0; j < 4; ++j)
      dst[(r0 + j)*16 + col] = cacc[j] * 0.14433757f;   // 1/sqrt(48)
  }

  // ---------------- Phase A1: sc = silu(s0), gates = sigmoid --------------------
  for (int i = t; i < 32 * 112; i += NT) {
    const int e = i / 112, p = i % 112;
    const float d0 = d00f[e];
    const float x  = o0[e*160 + p] * d0;
    const float sg = 1.f / (1.f + __expf(-x));
    if (p < 64) scs[e*64 + p] = f2b(x * sg);
    else        gates[e*48 + (p - 64)] = f2b(sg);
  }
  __syncthreads();  // B6

  // ---------------- Phase A2: rotate-back + gate -> g1/g2 staging --------------
  for (int i = t; i < 3072 + 5120; i += NT) {
    if (i < 3072) {
      const int e = i / 96, u = i % 96, c = u / 3, m = u % 3;
      const float* Dr = wig + (size_t)(eb0 + e) * 81;
      const float val = Dr[ 9 + 1 + m] * on1[e*48 + c]
                      + Dr[18 + 1 + m] * o0[e*160 + 112 + c]
                      + Dr[27 + 1 + m] * op1[e*48 + c];
      const float g = b2f(gates[e*48 + c]);
      u16* dst = (m < 2) ? (g1s + m*1024) : g1m2;
      dst[e*32 + c] = f2b(val * g);
    } else {
      const int q = i - 3072;
      const int e = q / 160, u = q % 160, c = u / 5, m = u % 5;
      float r = 0.f;
      if (c < 16) {
        const float* Dr = wig + (size_t)(eb0 + e) * 81;
        const float val = Dr[36 + 4 + m] * on2[e*16 + c]
                        + Dr[45 + 4 + m] * on1[e*48 + 32 + c]
                        + Dr[54 + 4 + m] * o0[e*160 + 144 + c]
                        + Dr[63 + 4 + m] * op1[e*48 + 32 + c]
                        + Dr[72 + 4 + m] * op2[e*16 + c];
        r = val * b2f(gates[e*48 + 32 + c]);
      }
      g2s[m*1024 + e*32 + c] = f2b(r);
    }
  }
  __syncthreads();  // B7

  // ---------------- Phase 3: final small matmuls (MFMA) + store ----------------
  for (int tau = w; tau < 30; tau += 4) {
    const int col16 = lane & 15;
    const int rbase = (lane >> 4) << 2;
    if (tau < 8) {            // y0: sc[32x64] @ lp_w0[64x64]
      const int mtt = tau >> 2, ntt = tau & 3;
      f32x4 a0 = ZERO4;
      #pragma unroll
      for (int kt = 0; kt < 2; ++kt) {
        const short8 a = *reinterpret_cast<const short8*>(
            scs + (mtt*16 + (lane & 15)) * 64 + kt*32 + (lane >> 4) * 8);
        a0 = MFMA(a, WF[(size_t)(FL0 + kt*4 + ntt) * 64 + lane], a0);
      }
      const int col = ntt*16 + col16;
      const float bias = lp_b0[col];
      #pragma unroll
      for (int j = 0; j < 4; ++j) {
        const int er = eb0 + mtt*16 + rbase + j;
        if (er < A) out[(size_t)er*240 + col] = a0[j] * 0.125f + bias;
      }
    } else if (tau < 20) {    // y1: g1[m][32x32] @ lp_w1[32x32]
      const int u = tau - 8;
      const int m = u >> 2, v = u & 3, mtt = v >> 1, ntt = v & 1;
      const u16* g1p = (m < 2) ? (g1s + m*1024) : g1m2;
      const short8 a = *reinterpret_cast<const short8*>(
          g1p + (mtt*16 + (lane & 15)) * 32 + (lane >> 4) * 8);
      f32x4 a0 = ZERO4;
      a0 = MFMA(a, WF[(size_t)(FL1 + ntt) * 64 + lane], a0);
      const int d = ntt*16 + col16;
      const int col = 64 + d*3 + m;
      #pragma unroll
      for (int j = 0; j < 4; ++j) {
        const int er = eb0 + mtt*16 + rbase + j;
        if (er < A) out[(size_t)er*240 + col] = a0[j] * 0.17677670f;  // 1/sqrt(32)
      }
    } else {                  // y2: g2[m][32x32(pad)] @ lp_w2[16x16]
      const int u = tau - 20;
      const int m = u >> 1, mtt = u & 1;
      const short8 a = *reinterpret_cast<const short8*>(
          g2s + m*1024 + (mtt*16 + (lane & 15)) * 32 + (lane >> 4) * 8);
      f32x4 a0 = ZERO4;
      a0 = MFMA(a, WF[(size_t)FL2 * 64 + lane], a0);
      const int col = 160 + col16*5 + m;
      #pragma unroll
      for (int j = 0; j < 4; ++j) {
        const int er = eb0 + mtt*16 + rbase + j;
        if (er < A) out[(size_t)er*240 + col] = a0[j] * 0.25f;        // 1/sqrt(16)
      }
    }
  }
}

extern "C" void kernel_launch(void* const* d_in, const int* in_sizes, int n_in,
                              void* d_out, int out_size, void* d_ws, size_t ws_size,
                              hipStream_t stream) {
  const float* latents  = (const float*)d_in[0];
  const float* nodef    = (const float*)d_in[1];
  const float* edgef    = (const float*)d_in[2];
  const float* wig      = (const float*)d_in[4];
  const float* ln_n_w0  = (const float*)d_in[5];
  const float* ln_n_b0  = (const float*)d_in[6];
  const float* ln_n_w1  = (const float*)d_in[7];
  const float* ln_n_w2  = (const float*)d_in[8];
  const float* ln_e_w0  = (const float*)d_in[9];
  const float* ln_e_b0  = (const float*)d_in[10];
  const float* ln_e_w1  = (const float*)d_in[11];
  const float* ln_e_w2  = (const float*)d_in[12];
  const float* so2_w0   = (const float*)d_in[13];
  const float* so2_w1r  = (const float*)d_in[14];
  const float* so2_w1i  = (const float*)d_in[15];
  const float* so2_w2r  = (const float*)d_in[16];
  const float* so2_w2i  = (const float*)d_in[17];
  const float* lp_w0    = (const float*)d_in[18];
  const float* lp_b0    = (const float*)d_in[19];
  const float* lp_w1    = (const float*)d_in[20];
  const float* lp_w2    = (const float*)d_in[21];
  const int*   edge_index   = (const int*)d_in[22];
  const int*   active_edges = (const int*)d_in[23];

  const int Etot = in_sizes[2] / 240;
  const int A    = in_sizes[23];

  u16* ws = (u16*)d_ws;   // needs NFRAG*1024 = 217,088 bytes

  // 1) swizzle all weights into bf16 B-fragment order
  const int pthreads = NFRAG * 64;
  hipLaunchKernelGGL(prep_w, dim3((pthreads + 255) / 256), dim3(256), 0, stream,
                     so2_w0, so2_w1r, so2_w1i, so2_w2r, so2_w2i,
                     lp_w0, lp_w1, lp_w2, ws);

  // 2) fused edge kernel
  const int grid = (A + EB - 1) / EB;
  hipLaunchKernelGGL(iel_mfma, dim3(grid), dim3(NT), 0, stream,
                     latents, nodef, edgef, wig,
                     ln_n_w0, ln_n_b0, ln_n_w1, ln_n_w2,
                     ln_e_w0, ln_e_b0, ln_e_w1, ln_e_w2,
                     lp_b0, edge_index, active_edges, ws,
                     (float*)d_out, Etot, A);
}

// Round 4
// 476.319 us; speedup vs baseline: 4.9024x; 2.5037x over previous
//
#include <hip/hip_runtime.h>
#include <hip/hip_bf16.h>
#include <math.h>

#define NT 256   // 4 waves
#define EB 16    // edges per block

using short8 = __attribute__((ext_vector_type(8))) short;
using f32x4  = __attribute__((ext_vector_type(4))) float;
typedef unsigned short u16;

#define MFMA(a,b,c) __builtin_amdgcn_mfma_f32_16x16x32_bf16((a),(b),(c),0,0,0)

// ---- swizzled-weight fragment table (each frag = 64 lanes x 8 bf16 = 1024B)
#define FW0   0     // so2_w0: K=464->480 (15 kt) x N=160 (10 nt) = 150 frags
#define FW1R  150   // w1r: K=144->160 (5) x N=48 (3) = 15
#define FW1I  165
#define FW1IN 180   // -w1i
#define FW2R  195   // w2r: K=48->64 (2) x N=16 (1) = 2
#define FW2I  197
#define FW2IN 199
#define FL0   201   // lp_w0: K=64 (2) x N=64 (4) = 8
#define FL1   209   // lp_w1: K=32 (1) x N=32 (2) = 2
#define FL2   211   // lp_w2: K=16->32 (1) x N=16 (1) = 1
#define NFRAG 212

__device__ __forceinline__ u16 f2b(float x) {
  __hip_bfloat16 h = __float2bfloat16(x);
  return *reinterpret_cast<u16*>(&h);
}
__device__ __forceinline__ float b2f(u16 u) {
  __hip_bfloat16 h; *reinterpret_cast<u16*>(&h) = u;
  return __bfloat162float(h);
}

// ---------------- weight pre-swizzle: f32 [K][N] -> bf16 B-fragments ----------
__global__ void prep_w(const float* __restrict__ w0,
                       const float* __restrict__ w1r, const float* __restrict__ w1i,
                       const float* __restrict__ w2r, const float* __restrict__ w2i,
                       const float* __restrict__ l0,  const float* __restrict__ l1,
                       const float* __restrict__ l2,  u16* __restrict__ ws) {
  const int g = blockIdx.x * 256 + threadIdx.x;
  if (g >= NFRAG * 64) return;
  const int frag = g >> 6, lane = g & 63;
  const float* src; int K, N, kt, nt; float sgn = 1.f;
  if (frag < FW1R)       { src = w0;  K = 464; N = 160; int f = frag;       kt = f/10; nt = f%10; }
  else if (frag < FW1I)  { src = w1r; K = 144; N = 48;  int f = frag-FW1R;  kt = f/3;  nt = f%3; }
  else if (frag < FW1IN) { src = w1i; K = 144; N = 48;  int f = frag-FW1I;  kt = f/3;  nt = f%3; }
  else if (frag < FW2R)  { src = w1i; K = 144; N = 48;  int f = frag-FW1IN; kt = f/3;  nt = f%3; sgn = -1.f; }
  else if (frag < FW2I)  { src = w2r; K = 48;  N = 16;  kt = frag-FW2R; nt = 0; }
  else if (frag < FW2IN) { src = w2i; K = 48;  N = 16;  kt = frag-FW2I; nt = 0; }
  else if (frag < FL0)   { src = w2i; K = 48;  N = 16;  kt = frag-FW2IN; nt = 0; sgn = -1.f; }
  else if (frag < FL1)   { src = l0;  K = 64;  N = 64;  int f = frag-FL0;   kt = f/4;  nt = f%4; }
  else if (frag < FL2)   { src = l1;  K = 32;  N = 32;  kt = 0; nt = frag-FL1; }
  else                   { src = l2;  K = 16;  N = 16;  kt = 0; nt = 0; }
  const int n  = nt*16 + (lane & 15);
  const int k0 = kt*32 + (lane >> 4) * 8;
  u16* dst = ws + (size_t)frag * 512 + lane * 8;
  #pragma unroll
  for (int j = 0; j < 8; ++j) {
    const int k = k0 + j;
    const float v = (k < K && n < N) ? src[k * N + n] * sgn : 0.f;
    dst[j] = f2b(v);
  }
}

// ------------------------------ main fused kernel -----------------------------
// LDS layout (bytes), total 40000 -> 4 blocks/CU:
//  0     m0  u16[16][488]        | alias: o0f f32[16][164] @0 ; g1s 3x u16[16][40] @10496
//  15616 p1  u16[16][168]        | alias: op1f f32[16][48] @15616 ; g2 plane4 @18688
//  20992 n1  u16[16][168]        | alias: on1f f32[16][48]
//  26368 p2  u16[16][72]         | alias: op2f f32[16][16]
//  28672 n2  u16[16][72]         | alias: on2f f32[16][16]
//  30976 scr f32[4][240]         | alias: gates u16[16][48] @30976 ; scs u16[16][72] @32512
//  34816 d00f f32[16]
//  34880 g2s 4x u16[16][40]   (ends 40000)
__global__ __launch_bounds__(NT, 4)
void iel_mfma(const float* __restrict__ latents,
              const float* __restrict__ nodef,
              const float* __restrict__ edgef,
              const float* __restrict__ wig,
              const float* __restrict__ ln_n_w0, const float* __restrict__ ln_n_b0,
              const float* __restrict__ ln_n_w1, const float* __restrict__ ln_n_w2,
              const float* __restrict__ ln_e_w0, const float* __restrict__ ln_e_b0,
              const float* __restrict__ ln_e_w1, const float* __restrict__ ln_e_w2,
              const float* __restrict__ lp_b0,
              const int* __restrict__ edge_index, const int* __restrict__ active_edges,
              const u16* __restrict__ ws,
              float* __restrict__ out,
              int Etot, int A)
{
  __shared__ __align__(16) char SMEM[40000];
  u16*   m0   = (u16*)(SMEM);
  u16*   p1   = (u16*)(SMEM + 15616);
  u16*   n1   = (u16*)(SMEM + 20992);
  u16*   p2   = (u16*)(SMEM + 26368);
  u16*   n2   = (u16*)(SMEM + 28672);
  float* o0f  = (float*)(SMEM);
  u16*   g1s  = (u16*)(SMEM + 10496);
  float* op1f = (float*)(SMEM + 15616);
  u16*   g2p4 = (u16*)(SMEM + 18688);
  float* on1f = (float*)(SMEM + 20992);
  float* op2f = (float*)(SMEM + 26368);
  float* on2f = (float*)(SMEM + 28672);
  float* scr  = (float*)(SMEM + 30976);
  u16*   gates= (u16*)(SMEM + 30976);
  u16*   scs  = (u16*)(SMEM + 32512);
  float* d00f = (float*)(SMEM + 34816);
  u16*   g2s  = (u16*)(SMEM + 34880);

  const short8* WF = (const short8*)ws;
  const int t    = threadIdx.x;
  const int lane = t & 63;
  const int w    = t >> 6;
  const int eb0  = blockIdx.x * EB;
  const f32x4 Z4 = {0.f, 0.f, 0.f, 0.f};

  // ---- pad clear (K-pad columns must be 0 for MFMA) ----
  {
    const int r = t >> 4, c = t & 15;
    m0[r*488 + 464 + c] = 0;
    p1[r*168 + 144 + c] = 0;
    n1[r*168 + 144 + c] = 0;
    p2[r*72  + 48  + c] = 0;
    n2[r*72  + 48  + c] = 0;
  }

  // ---- per-lane rotation invariants ----
  const int c1 = lane / 3, i1 = lane - c1*3;
  const bool q2lo = (lane < 32);
  const int u2 = q2lo ? lane + 64 : lane - 32;
  const int c2 = q2lo ? u2/3 : u2/5;
  const int i2 = q2lo ? (u2 - c2*3) : (u2 - c2*5);
  const int u3 = (lane < 48) ? lane + 32 : 79;
  const int c3 = u3/5, i3 = u3 - c3*5;
  const int o1 = (1+i1)*9 + 1;
  const int o2 = q2lo ? ((1+i2)*9 + 1) : ((4+i2)*9 + 4);
  const int o3 = (4+i3)*9 + 4;

  // ---- hoisted LN weights (node & edge) ----
  const float w0n = ln_n_w0[lane], b0n = ln_n_b0[lane];
  const float w0e = ln_e_w0[lane], b0e = ln_e_b0[lane];
  const float wAn = ln_n_w1[c1],   wAe = ln_e_w1[c1];
  const float wBn = q2lo ? ln_n_w1[c2] : ln_n_w2[c2];
  const float wBe = q2lo ? ln_e_w1[c2] : ln_e_w2[c2];
  const float wCn = ln_n_w2[c3],   wCe = ln_e_w2[c3];

  float* swr = scr + w * 240;

  // ---- edge index prefetch (wave's 4 edges) ----
  int aev[4], ecv[4], env[4];
  #pragma unroll
  for (int it = 0; it < 4; ++it) {
    const int e = eb0 + (w<<2) + it;
    aev[it] = active_edges[(e < A) ? e : (A-1)];
  }
  #pragma unroll
  for (int it = 0; it < 4; ++it) {
    ecv[it] = edge_index[aev[it]];
    env[it] = edge_index[Etot + aev[it]];
  }

  float crA[3][4], laA[2], crB[3][4], laB[2];

  auto issue = [&](int it, float (&cr)[3][4], float (&la)[2]) {
    const int e  = eb0 + (w<<2) + it;
    const int eS = (e < A) ? e : (A-1);
    const float* sp0 = nodef + (size_t)ecv[it]*240;
    const float* sp1 = edgef + (size_t)eS*240;
    const float* sp2 = nodef + (size_t)env[it]*240;
    cr[0][0]=sp0[lane]; cr[0][1]=sp0[lane+64]; cr[0][2]=sp0[lane+128]; cr[0][3]=(lane<48)?sp0[lane+192]:0.f;
    cr[1][0]=sp1[lane]; cr[1][1]=sp1[lane+64]; cr[1][2]=sp1[lane+128]; cr[1][3]=(lane<48)?sp1[lane+192]:0.f;
    cr[2][0]=sp2[lane]; cr[2][1]=sp2[lane+64]; cr[2][2]=sp2[lane+128]; cr[2][3]=(lane<48)?sp2[lane+192]:0.f;
    const float* lr = latents + (size_t)aev[it]*128;
    la[0] = lr[lane]; la[1] = lr[64+lane];
  };

  auto process = [&](int it, float (&cr)[3][4], float (&la)[2]) {
    const int e  = eb0 + (w<<2) + it;
    const int eS = (e < A) ? e : (A-1);
    const bool valid = (e < A);
    const int el = (w<<2) + it;
    const float* Dr = wig + (size_t)eS*81;
    // D coefficients (issued early; independent of reductions)
    const float d00 = Dr[0];
    float d1v[3], d2v[5], d3v[5];
    #pragma unroll
    for (int j = 0; j < 3; ++j) d1v[j] = Dr[o1+j];
    #pragma unroll
    for (int j = 0; j < 5; ++j) d2v[j] = Dr[o2+j];
    #pragma unroll
    for (int j = 0; j < 5; ++j) d3v[j] = Dr[o3+j];
    if (lane == 0) d00f[el] = d00;

    // 12 independent butterfly reductions (var via E[x^2]-mu^2)
    float sm[3], sq[3], S1[3], S2[3];
    #pragma unroll
    for (int r = 0; r < 3; ++r) {
      sm[r] = cr[r][0];
      sq[r] = cr[r][0]*cr[r][0];
      const float a = cr[r][1]*cr[r][1];
      const float b = cr[r][2]*cr[r][2];
      const float c = cr[r][3]*cr[r][3];
      S1[r] = a + (q2lo ? b : 0.f);
      S2[r] = (q2lo ? 0.f : b) + c;
    }
    #pragma unroll
    for (int s = 32; s > 0; s >>= 1) {
      #pragma unroll
      for (int r = 0; r < 3; ++r) {
        sm[r] += __shfl_xor(sm[r], s, 64);
        sq[r] += __shfl_xor(sq[r], s, 64);
        S1[r] += __shfl_xor(S1[r], s, 64);
        S2[r] += __shfl_xor(S2[r], s, 64);
      }
    }
    #pragma unroll
    for (int r = 0; r < 3; ++r) {
      const bool nd = (r != 1);
      const float mu  = sm[r] * (1.f/64.f);
      const float var = sq[r] * (1.f/64.f) - mu*mu;
      const float i0  = rsqrtf(var + 1e-8f);
      const float iv  = rsqrtf(0.5f*(S1[r]*(1.f/96.f) + S2[r]*(1.f/80.f)) + 1e-8f);
      // stage l1/l2 parts to wave-local scratch
      swr[64 + lane]  = cr[r][1] * iv * (nd ? wAn : wAe);
      swr[128 + lane] = cr[r][2] * iv * (nd ? wBn : wBe);
      if (lane < 48) swr[192 + lane] = cr[r][3] * iv * (nd ? wCn : wCe);
      asm volatile("s_waitcnt lgkmcnt(0)" ::: "memory");
      if (valid) {
        // q0: scalar channel (local, no LDS)
        const float y0 = (cr[r][0] - mu) * i0 * (nd ? w0n : w0e) + (nd ? b0n : b0e);
        m0[el*488 + r*112 + lane] = f2b(y0 * d00);
        // q1: 3-term rotation
        {
          const float* sb = swr + 64 + 3*c1;
          const float v = d1v[0]*sb[0] + d1v[1]*sb[1] + d1v[2]*sb[2];
          const u16 bv = f2b(v);
          if (i1 == 1)      m0[el*488 + r*112 + 64 + c1] = bv;
          else if (i1 == 2) p1[el*168 + r*48 + c1]       = bv;
          else              n1[el*168 + r*48 + c1]       = bv;
        }
        // q2
        if (q2lo) {
          const float* sb = swr + 64 + 3*c2;
          const float v = d2v[0]*sb[0] + d2v[1]*sb[1] + d2v[2]*sb[2];
          const u16 bv = f2b(v);
          if (i2 == 1)      m0[el*488 + r*112 + 64 + c2] = bv;
          else if (i2 == 2) p1[el*168 + r*48 + c2]       = bv;
          else              n1[el*168 + r*48 + c2]       = bv;
        } else {
          const float* sb = swr + 160 + 5*c2;
          const float v = d2v[0]*sb[0]+d2v[1]*sb[1]+d2v[2]*sb[2]+d2v[3]*sb[3]+d2v[4]*sb[4];
          const u16 bv = f2b(v);
          if (i2 == 2)      m0[el*488 + r*112 + 96 + c2] = bv;
          else if (i2 == 3) p1[el*168 + r*48 + 32 + c2]  = bv;
          else if (i2 == 1) n1[el*168 + r*48 + 32 + c2]  = bv;
          else if (i2 == 4) p2[el*72 + r*16 + c2]        = bv;
          else              n2[el*72 + r*16 + c2]        = bv;
        }
        // q3
        if (lane < 48) {
          const float* sb = swr + 160 + 5*c3;
          const float v = d3v[0]*sb[0]+d3v[1]*sb[1]+d3v[2]*sb[2]+d3v[3]*sb[3]+d3v[4]*sb[4];
          const u16 bv = f2b(v);
          if (i3 == 2)      m0[el*488 + r*112 + 96 + c3] = bv;
          else if (i3 == 3) p1[el*168 + r*48 + 32 + c3]  = bv;
          else if (i3 == 1) n1[el*168 + r*48 + 32 + c3]  = bv;
          else if (i3 == 4) p2[el*72 + r*16 + c3]        = bv;
          else              n2[el*72 + r*16 + c3]        = bv;
        }
      }
    }
    if (valid) {
      m0[el*488 + 336 + lane] = f2b(la[0]);
      m0[el*488 + 400 + lane] = f2b(la[1]);
    }
  };

  // ---- Phase 1 pipeline: issue next edge's loads before processing current ----
  issue(0, crA, laA);
  #pragma unroll
  for (int it = 0; it < 4; ++it) {
    if (it & 1) {
      if (it < 3) issue(it+1, crA, laA);
      process(it, crB, laB);
    } else {
      if (it < 3) issue(it+1, crB, laB);
      process(it, crA, laA);
    }
  }
  __syncthreads();  // B2: features ready

  // ---- Phase 2a: o0 = m0 @ so2_w0 (10 N-tiles over 4 waves) ----
  f32x4 acc2a[3] = {Z4, Z4, Z4};
  {
    const u16* abase = m0 + (lane & 15)*488 + (lane >> 4)*8;
    #pragma unroll
    for (int kt = 0; kt < 15; ++kt) {
      const short8 a = *reinterpret_cast<const short8*>(abase + kt*32);
      #pragma unroll
      for (int i = 0; i < 3; ++i) {
        const int nt = w + 4*i;
        if (nt < 10)
          acc2a[i] = MFMA(a, WF[(size_t)(FW0 + kt*10 + nt)*64 + lane], acc2a[i]);
      }
    }
  }
  __syncthreads();  // B3: all m0 reads done

  // write o0 (aliases m0), then 2b/2c MFMAs
  {
    #pragma unroll
    for (int i = 0; i < 3; ++i) {
      const int nt = w + 4*i;
      if (nt < 10) {
        const int col = nt*16 + (lane & 15);
        const int r0 = (lane >> 4)*4;
        #pragma unroll
        for (int j = 0; j < 4; ++j)
          o0f[(r0+j)*164 + col] = acc2a[i][j] * 0.046423835f;  // 1/sqrt(464)
      }
    }
  }
  f32x4 acc2b[2] = {Z4, Z4};
  f32x4 acc2c = Z4;
  {
    const u16* pbase = p1 + (lane & 15)*168 + (lane >> 4)*8;
    const u16* nbase = n1 + (lane & 15)*168 + (lane >> 4)*8;
    #pragma unroll
    for (int kt = 0; kt < 5; ++kt) {
      const short8 pa = *reinterpret_cast<const short8*>(pbase + kt*32);
      const short8 na = *reinterpret_cast<const short8*>(nbase + kt*32);
      #pragma unroll
      for (int i = 0; i < 2; ++i) {
        const int tau = w + 4*i;
        if (tau < 6) {
          const int isOn = (tau >= 3) ? 1 : 0;
          const int nt2 = tau - 3*isOn;
          acc2b[i] = MFMA(pa, WF[(size_t)((isOn?FW1I:FW1R)  + kt*3 + nt2)*64 + lane], acc2b[i]);
          acc2b[i] = MFMA(na, WF[(size_t)((isOn?FW1R:FW1IN) + kt*3 + nt2)*64 + lane], acc2b[i]);
        }
      }
    }
    if (w >= 2) {
      const u16* pb2 = p2 + (lane & 15)*72 + (lane >> 4)*8;
      const u16* nb2 = n2 + (lane & 15)*72 + (lane >> 4)*8;
      const int isOn2 = (w == 3);
      #pragma unroll
      for (int kt = 0; kt < 2; ++kt) {
        const short8 pa = *reinterpret_cast<const short8*>(pb2 + kt*32);
        const short8 na = *reinterpret_cast<const short8*>(nb2 + kt*32);
        acc2c = MFMA(pa, WF[(size_t)((isOn2?FW2I:FW2R)  + kt)*64 + lane], acc2c);
        acc2c = MFMA(na, WF[(size_t)((isOn2?FW2R:FW2IN) + kt)*64 + lane], acc2c);
      }
    }
  }
  __syncthreads();  // B4: p1/n1/p2/n2 reads done, o0 writes done

  // write op1/on1/op2/on2 (alias feature regions)
  {
    #pragma unroll
    for (int i = 0; i < 2; ++i) {
      const int tau = w + 4*i;
      if (tau < 6) {
        const int isOn = (tau >= 3) ? 1 : 0;
        const int nt2 = tau - 3*isOn;
        float* dst = isOn ? on1f : op1f;
        const int col = nt2*16 + (lane & 15);
        const int r0 = (lane >> 4)*4;
        #pragma unroll
        for (int j = 0; j < 4; ++j)
          dst[(r0+j)*48 + col] = acc2b[i][j] * (1.f/12.f);
      }
    }
    if (w >= 2) {
      float* dst = (w == 3) ? on2f : op2f;
      const int r0 = (lane >> 4)*4;
      #pragma unroll
      for (int j = 0; j < 4; ++j)
        dst[(r0+j)*16 + (lane & 15)] = acc2c[j] * 0.14433757f;  // 1/sqrt(48)
    }
  }
  // A1: silu + gates (reads o0, writes scs/gates in scr region)
  {
    const int e = t >> 4, l16 = t & 15;
    const float d0 = d00f[e];
    #pragma unroll
    for (int k = 0; k < 7; ++k) {
      const int p = l16 + 16*k;
      const float x = o0f[e*164 + p] * d0;
      const float sg = 1.f/(1.f + __expf(-x));
      if (p < 64) scs[e*72 + p] = f2b(x * sg);
      else        gates[e*48 + (p - 64)] = f2b(sg);
    }
  }
  __syncthreads();  // B5

  // A2: rotate-back + gate -> g1/g2 bf16 staging
  {
    const int e = t >> 4, l16 = t & 15;
    const int eg = eb0 + e;
    const float* Dr = wig + (size_t)((eg < A) ? eg : (A-1))*81;
    #pragma unroll
    for (int k = 0; k < 6; ++k) {
      const int item = l16 + 16*k;          // 0..95
      const int c = item/3, m = item - 3*c;
      const float val = Dr[ 9+1+m]*on1f[e*48 + c]
                      + Dr[18+1+m]*o0f[e*164 + 112 + c]
                      + Dr[27+1+m]*op1f[e*48 + c];
      const float g = b2f(gates[e*48 + c]);
      g1s[m*640 + e*40 + c] = f2b(val * g);
    }
    #pragma unroll
    for (int k = 0; k < 10; ++k) {
      const int item = l16 + 16*k;          // 0..159
      const int c = item/5, m = item - 5*c;
      float rv = 0.f;
      if (c < 16) {
        const float val = Dr[36+4+m]*on2f[e*16 + c]
                        + Dr[45+4+m]*on1f[e*48 + 32 + c]
                        + Dr[54+4+m]*o0f[e*164 + 144 + c]
                        + Dr[63+4+m]*op1f[e*48 + 32 + c]
                        + Dr[72+4+m]*op2f[e*16 + c];
        rv = val * b2f(gates[e*48 + 32 + c]);
      }
      u16* dst = (m < 4) ? (g2s + m*640) : g2p4;
      dst[e*40 + c] = f2b(rv);
    }
  }
  __syncthreads();  // B6

  // ---- Phase 3: final small matmuls (15 MFMA tasks over 4 waves) + store ----
  for (int tau = w; tau < 15; tau += 4) {
    const int col16 = lane & 15;
    const int r0 = (lane >> 4)*4;
    if (tau < 4) {            // y0: sc[16x64] @ lp_w0
      const int ntt = tau;
      f32x4 a0 = Z4;
      #pragma unroll
      for (int kt = 0; kt < 2; ++kt) {
        const short8 a = *reinterpret_cast<const short8*>(
            scs + (lane & 15)*72 + kt*32 + (lane >> 4)*8);
        a0 = MFMA(a, WF[(size_t)(FL0 + kt*4 + ntt)*64 + lane], a0);
      }
      const int col = ntt*16 + col16;
      const float bias = lp_b0[col];
      #pragma unroll
      for (int j = 0; j < 4; ++j) {
        const int er = eb0 + r0 + j;
        if (er < A) out[(size_t)er*240 + col] = a0[j]*0.125f + bias;
      }
    } else if (tau < 10) {    // y1: g1[m][16x32] @ lp_w1
      const int u = tau - 4, m = u >> 1, ntt = u & 1;
      const short8 a = *reinterpret_cast<const short8*>(
          g1s + m*640 + (lane & 15)*40 + (lane >> 4)*8);
      f32x4 a0 = MFMA(a, WF[(size_t)(FL1 + ntt)*64 + lane], Z4);
      const int d = ntt*16 + col16;
      const int col = 64 + d*3 + m;
      #pragma unroll
      for (int j = 0; j < 4; ++j) {
        const int er = eb0 + r0 + j;
        if (er < A) out[(size_t)er*240 + col] = a0[j]*0.17677670f;  // 1/sqrt(32)
      }
    } else {                  // y2: g2[m][16x32(pad)] @ lp_w2
      const int m = tau - 10;
      const u16* gp = (m < 4) ? (g2s + m*640) : g2p4;
      const short8 a = *reinterpret_cast<const short8*>(
          gp + (lane & 15)*40 + (lane >> 4)*8);
      f32x4 a0 = MFMA(a, WF[(size_t)FL2*64 + lane], Z4);
      const int col = 160 + col16*5 + m;
      #pragma unroll
      for (int j = 0; j < 4; ++j) {
        const int er = eb0 + r0 + j;
        if (er < A) out[(size_t)er*240 + col] = a0[j]*0.25f;        // 1/sqrt(16)
      }
    }
  }
}

extern "C" void kernel_launch(void* const* d_in, const int* in_sizes, int n_in,
                              void* d_out, int out_size, void* d_ws, size_t ws_size,
                              hipStream_t stream) {
  const float* latents  = (const float*)d_in[0];
  const float* nodef    = (const float*)d_in[1];
  const float* edgef    = (const float*)d_in[2];
  const float* wig      = (const float*)d_in[4];
  const float* ln_n_w0  = (const float*)d_in[5];
  const float* ln_n_b0  = (const float*)d_in[6];
  const float* ln_n_w1  = (const float*)d_in[7];
  const float* ln_n_w2  = (const float*)d_in[8];
  const float* ln_e_w0  = (const float*)d_in[9];
  const float* ln_e_b0  = (const float*)d_in[10];
  const float* ln_e_w1  = (const float*)d_in[11];
  const float* ln_e_w2  = (const float*)d_in[12];
  const float* so2_w0   = (const float*)d_in[13];
  const float* so2_w1r  = (const float*)d_in[14];
  const float* so2_w1i  = (const float*)d_in[15];
  const float* so2_w2r  = (const float*)d_in[16];
  const float* so2_w2i  = (const float*)d_in[17];
  const float* lp_w0    = (const float*)d_in[18];
  const float* lp_b0    = (const float*)d_in[19];
  const float* lp_w1    = (const float*)d_in[20];
  const float* lp_w2    = (const float*)d_in[21];
  const int*   edge_index   = (const int*)d_in[22];
  const int*   active_edges = (const int*)d_in[23];

  const int Etot = in_sizes[2] / 240;
  const int A    = in_sizes[23];

  u16* ws = (u16*)d_ws;   // needs NFRAG*1024 = 217,088 bytes

  const int pthreads = NFRAG * 64;
  hipLaunchKernelGGL(prep_w, dim3((pthreads + 255) / 256), dim3(256), 0, stream,
                     so2_w0, so2_w1r, so2_w1i, so2_w2r, so2_w2i,
                     lp_w0, lp_w1, lp_w2, ws);

  const int grid = (A + EB - 1) / EB;
  hipLaunchKernelGGL(iel_mfma, dim3(grid), dim3(NT), 0, stream,
                     latents, nodef, edgef, wig,
                     ln_n_w0, ln_n_b0, ln_n_w1, ln_n_w2,
                     ln_e_w0, ln_e_b0, ln_e_w1, ln_e_w2,
                     lp_b0, edge_index, active_edges, ws,
                     (float*)d_out, Etot, A);
}

// Round 7
// 448.736 us; speedup vs baseline: 5.2038x; 1.0615x over previous
//
#include <hip/hip_runtime.h>
#include <hip/hip_bf16.h>
#include <math.h>

#define NT 256   // 4 waves
#define EB 16    // edges per block

using sv4    = __attribute__((ext_vector_type(4))) short;
using short8 = __attribute__((ext_vector_type(8))) short;
using f32x4  = __attribute__((ext_vector_type(4))) float;
typedef unsigned short u16;

#define MFMA(a,b,c) __builtin_amdgcn_mfma_f32_16x16x32_bf16((a),(b),(c),0,0,0)

// ---- swizzled-weight fragment table (each frag = 64 lanes x 8 bf16 = 1024B)
#define FW0   0     // so2_w0: K=464->480 (15 kt) x N=160 (10 nt) = 150 frags
#define FW1R  150   // w1r: K=144->160 (5) x N=48 (3) = 15
#define FW1I  165
#define FW1IN 180   // -w1i
#define FW2R  195   // w2r: K=48->64 (2) x N=16 (1) = 2
#define FW2I  197
#define FW2IN 199
#define FL0   201   // lp_w0: K=64 (2) x N=64 (4) = 8
#define FL1   209   // lp_w1: K=32 (1) x N=32 (2) = 2
#define FL2   211   // lp_w2: K=16->32 (1) x N=16 (1) = 1
#define NFRAG 212
#define WS_NLS_OFF (NFRAG * 512)   // u16 elements offset of node-LN table in ws

__device__ __forceinline__ u16 f2b(float x) {
  __hip_bfloat16 h = __float2bfloat16(x);
  return *reinterpret_cast<u16*>(&h);
}
__device__ __forceinline__ float b2f(u16 u) {
  __hip_bfloat16 h; *reinterpret_cast<u16*>(&h) = u;
  return __bfloat162float(h);
}
__device__ __forceinline__ sv4    ld4(const u16* p){ return *reinterpret_cast<const sv4*>(p); }
__device__ __forceinline__ short8 ld8(const u16* p){ return *reinterpret_cast<const short8*>(p); }

// ---------------- weight pre-swizzle: f32 [K][N] -> bf16 B-fragments ----------
__global__ void prep_w(const float* __restrict__ w0,
                       const float* __restrict__ w1r, const float* __restrict__ w1i,
                       const float* __restrict__ w2r, const float* __restrict__ w2i,
                       const float* __restrict__ l0,  const float* __restrict__ l1,
                       const float* __restrict__ l2,  u16* __restrict__ ws) {
  const int g = blockIdx.x * 256 + threadIdx.x;
  if (g >= NFRAG * 64) return;
  const int frag = g >> 6, lane = g & 63;
  const float* src; int K, N, kt, nt; float sgn = 1.f;
  if (frag < FW1R)       { src = w0;  K = 464; N = 160; int f = frag;       kt = f/10; nt = f%10; }
  else if (frag < FW1I)  { src = w1r; K = 144; N = 48;  int f = frag-FW1R;  kt = f/3;  nt = f%3; }
  else if (frag < FW1IN) { src = w1i; K = 144; N = 48;  int f = frag-FW1I;  kt = f/3;  nt = f%3; }
  else if (frag < FW2R)  { src = w1i; K = 144; N = 48;  int f = frag-FW1IN; kt = f/3;  nt = f%3; sgn = -1.f; }
  else if (frag < FW2I)  { src = w2r; K = 48;  N = 16;  kt = frag-FW2R; nt = 0; }
  else if (frag < FW2IN) { src = w2i; K = 48;  N = 16;  kt = frag-FW2I; nt = 0; }
  else if (frag < FL0)   { src = w2i; K = 48;  N = 16;  kt = frag-FW2IN; nt = 0; sgn = -1.f; }
  else if (frag < FL1)   { src = l0;  K = 64;  N = 64;  int f = frag-FL0;   kt = f/4;  nt = f%4; }
  else if (frag < FL2)   { src = l1;  K = 32;  N = 32;  kt = 0; nt = frag-FL1; }
  else                   { src = l2;  K = 16;  N = 16;  kt = 0; nt = 0; }
  const int n  = nt*16 + (lane & 15);
  const int k0 = kt*32 + (lane >> 4) * 8;
  u16* dst = ws + (size_t)frag * 512 + lane * 8;
  #pragma unroll
  for (int j = 0; j < 8; ++j) {
    const int k = k0 + j;
    const float v = (k < K && n < N) ? src[k * N + n] * sgn : 0.f;
    dst[j] = f2b(v);
  }
}

// ---------------- node pre-LN: f32[N][240] -> packed bf16[N][320] -------------
// layout per row: [0..63] y0 ; [64+4c+j] l1 triple c<32,j<3 (pad j=3) ;
//                 [192+8c+j] l2 quint c<16,j<5 (pads j=5..7)
__global__ void ln_nodes(const float* __restrict__ nodef,
                         const float* __restrict__ w0, const float* __restrict__ b0,
                         const float* __restrict__ w1, const float* __restrict__ w2,
                         u16* __restrict__ nls, int N) {
  const int row  = blockIdx.x * 4 + (threadIdx.x >> 6);
  const int lane = threadIdx.x & 63;
  if (row >= N) return;
  const float* src = nodef + (size_t)row * 240;
  const float v0 = src[lane];
  const float v1 = src[lane + 64];
  const float v2 = src[lane + 128];
  const float v3 = (lane < 48) ? src[lane + 192] : 0.f;
  const bool lo = (lane < 32);
  float sm = v0, sq = v0*v0;
  float S1 = v1*v1 + (lo ? v2*v2 : 0.f);
  float S2 = (lo ? 0.f : v2*v2) + v3*v3;
  #pragma unroll
  for (int s = 32; s > 0; s >>= 1) {
    sm += __shfl_xor(sm, s, 64); sq += __shfl_xor(sq, s, 64);
    S1 += __shfl_xor(S1, s, 64); S2 += __shfl_xor(S2, s, 64);
  }
  const float mu  = sm * (1.f/64.f);
  const float i0  = rsqrtf(sq*(1.f/64.f) - mu*mu + 1e-8f);
  const float inv = rsqrtf(0.5f*(S1*(1.f/96.f) + S2*(1.f/80.f)) + 1e-8f);
  u16* dst = nls + (size_t)row * 320;
  dst[lane] = f2b((v0 - mu) * i0 * w0[lane] + b0[lane]);
  { const int u = lane;      const int c = u/3, j = u-3*c; dst[64 + 4*c + j]  = f2b(v1*inv*w1[c]); }
  if (lo) { const int u = lane+64; const int c = u/3, j = u-3*c; dst[64 + 4*c + j]  = f2b(v2*inv*w1[c]); }
  else    { const int u = lane-32; const int c = u/5, j = u-5*c; dst[192 + 8*c + j] = f2b(v2*inv*w2[c]); }
  if (lane < 48) { const int u = lane+32; const int c = u/5, j = u-5*c; dst[192 + 8*c + j] = f2b(v3*inv*w2[c]); }
  if (lane < 32) dst[64 + 4*lane + 3] = 0;
  if (lane < 48) { const int c = lane/3, j = lane-3*c; dst[192 + 8*c + 5 + j] = 0; }
}

// ------------------------------ main fused kernel -----------------------------
// LDS layout (bytes), total 38816 -> 4 blocks/CU:
//  0     m0  u16[16 x 472 +8]    | alias: o0f f32[16][164] @0 ; g1s 3x[16x40]u16 @10496
//  15120 p1  u16[16 x 152 +8]    | alias: op1f f32[16][52]
//  20000 n1  u16[16 x 152 +8]    | alias: on1f f32[16][52]
//  24880 p2  u16[16 x 56 +8]     | alias: op2f f32[16][20]
//  26688 n2  u16[16 x 56 +8]     | alias: on2f f32[16][20]
//  28496 scr f32[4][240]         | alias: gates u16[16][48] @28496 ; scs u16[16x72] @30032
//  32336 Dc  f32[16][40]  (compact Wigner: [0]=d00, [1+a*3+b]=l1, [12+a*5+b]=l2)
//  34896 g2s 5 x u16[16x24 +8]   (ends 38816)
__global__ __launch_bounds__(NT, 4)
void iel_mfma(const float* __restrict__ latents,
              const float* __restrict__ edgef,
              const float* __restrict__ wig,
              const float* __restrict__ ln_e_w0, const float* __restrict__ ln_e_b0,
              const float* __restrict__ ln_e_w1, const float* __restrict__ ln_e_w2,
              const float* __restrict__ lp_b0,
              const int* __restrict__ edge_index, const int* __restrict__ active_edges,
              const u16* __restrict__ ws, const u16* __restrict__ nls,
              float* __restrict__ out,
              int Etot, int A)
{
  __shared__ __align__(16) char SMEM[38816];
  u16*   m0   = (u16*)(SMEM);
  u16*   p1   = (u16*)(SMEM + 15120);
  u16*   n1   = (u16*)(SMEM + 20000);
  u16*   p2   = (u16*)(SMEM + 24880);
  u16*   n2   = (u16*)(SMEM + 26688);
  float* scr  = (float*)(SMEM + 28496);
  float* Dc   = (float*)(SMEM + 32336);
  u16*   g2s  = (u16*)(SMEM + 34896);
  float* o0f  = (float*)(SMEM);
  u16*   g1s  = (u16*)(SMEM + 10496);
  float* op1f = (float*)(SMEM + 15120);
  float* on1f = (float*)(SMEM + 20000);
  float* op2f = (float*)(SMEM + 24880);
  float* on2f = (float*)(SMEM + 26688);
  u16*   gates= (u16*)(SMEM + 28496);
  u16*   scs  = (u16*)(SMEM + 30032);

  const short8* WF = (const short8*)ws;
  const int t    = threadIdx.x;
  const int lane = t & 63;
  const int w    = t >> 6;
  const int eb0  = blockIdx.x * EB;
  const f32x4 Z4 = {0.f, 0.f, 0.f, 0.f};

  // ---- pad/tail clear: MFMA A-operands must never read NaN garbage ----------
  // (B-side zeros do NOT protect: 0 * NaN = NaN.)
  {
    const int r = t >> 4, c = t & 15;   // r<16, c<16
    if (c < 8) {
      m0[r*472 + 464 + c] = 0;
      p1[r*152 + 144 + c] = 0;
      n1[r*152 + 144 + c] = 0;
      p2[r*56  + 48  + c] = 0;
      n2[r*56  + 48  + c] = 0;
      #pragma unroll
      for (int m = 0; m < 5; ++m) g2s[m*392 + r*24 + 16 + c] = 0;
    }
    if (t < 8) {
      m0[16*472 + t] = 0;
      p1[16*152 + t] = 0;
      n1[16*152 + t] = 0;
      p2[16*56  + t] = 0;
      n2[16*56  + t] = 0;
      #pragma unroll
      for (int m = 0; m < 5; ++m) g2s[m*392 + 384 + t] = 0;
    }
  }

  // ---- per-lane rotation invariants ----
  const int c1 = lane / 3, i1 = lane - c1*3;
  const bool q2lo = (lane < 32);
  const int u2 = q2lo ? lane + 64 : lane - 32;
  const int c2 = q2lo ? u2/3 : u2/5;
  const int i2 = q2lo ? (u2 - c2*3) : (u2 - c2*5);
  const int u3 = (lane < 48) ? lane + 32 : 79;
  const int c3 = u3/5, i3 = u3 - c3*5;

  // ---- hoisted edge-LN weights ----
  const float w0e = ln_e_w0[lane], b0e = ln_e_b0[lane];
  const float wAe = ln_e_w1[c1];
  const float wBe = q2lo ? ln_e_w1[c2] : ln_e_w2[c2];
  const float wCe = ln_e_w2[c3];

  float* swr = scr + w * 240;

  // ---- edge index prefetch (wave's 4 edges) ----
  int aev[4], ecv[4], env[4];
  #pragma unroll
  for (int it = 0; it < 4; ++it) {
    const int e = eb0 + (w<<2) + it;
    aev[it] = active_edges[(e < A) ? e : (A-1)];
  }
  #pragma unroll
  for (int it = 0; it < 4; ++it) {
    ecv[it] = edge_index[aev[it]];
    env[it] = edge_index[Etot + aev[it]];
  }

  // ---- stage compact Wigner D for this wave's 4 edges ----
  #pragma unroll
  for (int it = 0; it < 4; ++it) {
    const int el = (w<<2) + it;
    const int e  = eb0 + el;
    const int eS = (e < A) ? e : (A-1);
    if (lane < 35) {
      int src, dst;
      if (lane == 0)      { src = 0; dst = 0; }
      else if (lane < 10) { const int a=(lane-1)/3, b=(lane-1)-3*((lane-1)/3); src=(1+a)*9+(1+b); dst=lane; }
      else                { const int a=(lane-10)/5, b=(lane-10)-5*((lane-10)/5); src=(4+a)*9+(4+b); dst=lane+2; }
      Dc[el*40 + dst] = wig[(size_t)eS*81 + src];
    }
  }

  struct ER {
    u16 q0a, q0b;
    sv4 t1a, t1b, t2aa, t2ab;
    short8 t2ba, t2bb, t3a, t3b;
    float e0, e1, e2, e3, l0, l1;
  };
  ER RA, RB;

  auto issue = [&](int it, ER& R) {
    const int e  = eb0 + (w<<2) + it;
    const int eS = (e < A) ? e : (A-1);
    const u16* nba = nls + (size_t)ecv[it]*320;
    const u16* nbb = nls + (size_t)env[it]*320;
    R.q0a = nba[lane];              R.q0b = nbb[lane];
    R.t1a = ld4(nba + 64 + 4*c1);   R.t1b = ld4(nbb + 64 + 4*c1);
    if (q2lo) { R.t2aa = ld4(nba + 64 + 4*c2);  R.t2ab = ld4(nbb + 64 + 4*c2); }
    else      { R.t2ba = ld8(nba + 192 + 8*c2); R.t2bb = ld8(nbb + 192 + 8*c2); }
    if (lane < 48) { R.t3a = ld8(nba + 192 + 8*c3); R.t3b = ld8(nbb + 192 + 8*c3); }
    const float* ep = edgef + (size_t)eS*240;
    R.e0 = ep[lane]; R.e1 = ep[lane+64]; R.e2 = ep[lane+128];
    R.e3 = (lane < 48) ? ep[lane+192] : 0.f;
    const float* lr = latents + (size_t)aev[it]*128;
    R.l0 = lr[lane]; R.l1 = lr[64+lane];
  };

  auto nodeWrite = [&](int el, int r, u16 q0, sv4 t1, sv4 t2a, short8 t2b, short8 t3,
                       float d00, const float* d1v, const float* d2v, const float* d3v) {
    const int mb = el*472 + r*112;
    m0[mb + lane] = f2b(b2f(q0) * d00);
    {
      const float v = d1v[0]*b2f((u16)t1[0]) + d1v[1]*b2f((u16)t1[1]) + d1v[2]*b2f((u16)t1[2]);
      const u16 bv = f2b(v);
      if (i1 == 1)      m0[mb + 64 + c1] = bv;
      else if (i1 == 2) p1[el*152 + r*48 + c1] = bv;
      else              n1[el*152 + r*48 + c1] = bv;
    }
    if (q2lo) {
      const float v = d2v[0]*b2f((u16)t2a[0]) + d2v[1]*b2f((u16)t2a[1]) + d2v[2]*b2f((u16)t2a[2]);
      const u16 bv = f2b(v);
      if (i2 == 1)      m0[mb + 64 + c2] = bv;
      else if (i2 == 2) p1[el*152 + r*48 + c2] = bv;
      else              n1[el*152 + r*48 + c2] = bv;
    } else {
      float v = 0.f;
      #pragma unroll
      for (int j = 0; j < 5; ++j) v += d2v[j]*b2f((u16)t2b[j]);
      const u16 bv = f2b(v);
      if (i2 == 2)      m0[mb + 96 + c2] = bv;
      else if (i2 == 3) p1[el*152 + r*48 + 32 + c2] = bv;
      else if (i2 == 1) n1[el*152 + r*48 + 32 + c2] = bv;
      else if (i2 == 4) p2[el*56 + r*16 + c2] = bv;
      else              n2[el*56 + r*16 + c2] = bv;
    }
    if (lane < 48) {
      float v = 0.f;
      #pragma unroll
      for (int j = 0; j < 5; ++j) v += d3v[j]*b2f((u16)t3[j]);
      const u16 bv = f2b(v);
      if (i3 == 2)      m0[mb + 96 + c3] = bv;
      else if (i3 == 3) p1[el*152 + r*48 + 32 + c3] = bv;
      else if (i3 == 1) n1[el*152 + r*48 + 32 + c3] = bv;
      else if (i3 == 4) p2[el*56 + r*16 + c3] = bv;
      else              n2[el*56 + r*16 + c3] = bv;
    }
  };

  auto process = [&](int it, ER& R) {
    const int el = (w<<2) + it;
    const float* DcE = Dc + el*40;
    const float d00 = DcE[0];
    float d1v[3], d2v[5], d3v[5];
    #pragma unroll
    for (int j = 0; j < 3; ++j) d1v[j] = DcE[1 + i1*3 + j];
    #pragma unroll
    for (int j = 0; j < 5; ++j) d2v[j] = q2lo ? ((j < 3) ? DcE[1 + i2*3 + j] : 0.f)
                                              : DcE[12 + i2*5 + j];
    #pragma unroll
    for (int j = 0; j < 5; ++j) d3v[j] = DcE[12 + i3*5 + j];

    nodeWrite(el, 0, R.q0a, R.t1a, R.t2aa, R.t2ba, R.t3a, d00, d1v, d2v, d3v);
    nodeWrite(el, 2, R.q0b, R.t1b, R.t2ab, R.t2bb, R.t3b, d00, d1v, d2v, d3v);

    // edge row (r=1): full LN
    {
      const float v0 = R.e0, v1 = R.e1, v2 = R.e2, v3 = R.e3;
      float sm = v0, sq = v0*v0;
      float S1 = v1*v1 + (q2lo ? v2*v2 : 0.f);
      float S2 = (q2lo ? 0.f : v2*v2) + v3*v3;
      #pragma unroll
      for (int s = 32; s > 0; s >>= 1) {
        sm += __shfl_xor(sm, s, 64); sq += __shfl_xor(sq, s, 64);
        S1 += __shfl_xor(S1, s, 64); S2 += __shfl_xor(S2, s, 64);
      }
      const float mu = sm * (1.f/64.f);
      const float i0 = rsqrtf(sq*(1.f/64.f) - mu*mu + 1e-8f);
      const float iv = rsqrtf(0.5f*(S1*(1.f/96.f) + S2*(1.f/80.f)) + 1e-8f);
      swr[64 + lane]  = v1 * iv * wAe;
      swr[128 + lane] = v2 * iv * wBe;
      if (lane < 48) swr[192 + lane] = v3 * iv * wCe;
      asm volatile("s_waitcnt lgkmcnt(0)" ::: "memory");
      const int mb = el*472 + 112;
      m0[mb + lane] = f2b(((v0 - mu)*i0*w0e + b0e) * d00);
      {
        const float* sb = swr + 64 + 3*c1;
        const float v = d1v[0]*sb[0] + d1v[1]*sb[1] + d1v[2]*sb[2];
        const u16 bv = f2b(v);
        if (i1 == 1)      m0[mb + 64 + c1] = bv;
        else if (i1 == 2) p1[el*152 + 48 + c1] = bv;
        else              n1[el*152 + 48 + c1] = bv;
      }
      if (q2lo) {
        const float* sb = swr + 64 + 3*c2;
        const float v = d2v[0]*sb[0] + d2v[1]*sb[1] + d2v[2]*sb[2];
        const u16 bv = f2b(v);
        if (i2 == 1)      m0[mb + 64 + c2] = bv;
        else if (i2 == 2) p1[el*152 + 48 + c2] = bv;
        else              n1[el*152 + 48 + c2] = bv;
      } else {
        const float* sb = swr + 160 + 5*c2;
        float v = 0.f;
        #pragma unroll
        for (int j = 0; j < 5; ++j) v += d2v[j]*sb[j];
        const u16 bv = f2b(v);
        if (i2 == 2)      m0[mb + 96 + c2] = bv;
        else if (i2 == 3) p1[el*152 + 48 + 32 + c2] = bv;
        else if (i2 == 1) n1[el*152 + 48 + 32 + c2] = bv;
        else if (i2 == 4) p2[el*56 + 16 + c2] = bv;
        else              n2[el*56 + 16 + c2] = bv;
      }
      if (lane < 48) {
        const float* sb = swr + 160 + 5*c3;
        float v = 0.f;
        #pragma unroll
        for (int j = 0; j < 5; ++j) v += d3v[j]*sb[j];
        const u16 bv = f2b(v);
        if (i3 == 2)      m0[mb + 96 + c3] = bv;
        else if (i3 == 3) p1[el*152 + 48 + 32 + c3] = bv;
        else if (i3 == 1) n1[el*152 + 48 + 32 + c3] = bv;
        else if (i3 == 4) p2[el*56 + 16 + c3] = bv;
        else              n2[el*56 + 16 + c3] = bv;
      }
    }
    m0[el*472 + 336 + lane] = f2b(R.l0);
    m0[el*472 + 400 + lane] = f2b(R.l1);
  };

  // ---- Phase 1 software pipeline ----
  issue(0, RA);
  issue(1, RB); process(0, RA);
  issue(2, RA); process(1, RB);
  issue(3, RB); process(2, RA);
  process(3, RB);
  __syncthreads();  // B2: features + Dc ready

  // ---- Phase 2a: o0 = m0 @ so2_w0 (10 N-tiles over 4 waves) ----
  f32x4 acc2a[3] = {Z4, Z4, Z4};
  {
    const u16* abase = m0 + (lane & 15)*472 + (lane >> 4)*8;
    #pragma unroll
    for (int kt = 0; kt < 15; ++kt) {
      const short8 a = *reinterpret_cast<const short8*>(abase + kt*32);
      #pragma unroll
      for (int i = 0; i < 3; ++i) {
        const int nt = w + 4*i;
        if (nt < 10)
          acc2a[i] = MFMA(a, WF[(size_t)(FW0 + kt*10 + nt)*64 + lane], acc2a[i]);
      }
    }
  }
  // ---- Phase 2b/2c compute (reads p1/n1/p2/n2, not yet overwritten) ----
  f32x4 acc2b[2] = {Z4, Z4};
  f32x4 acc2c = Z4;
  {
    const u16* pbase = p1 + (lane & 15)*152 + (lane >> 4)*8;
    const u16* nbase = n1 + (lane & 15)*152 + (lane >> 4)*8;
    #pragma unroll
    for (int kt = 0; kt < 5; ++kt) {
      const short8 pa = *reinterpret_cast<const short8*>(pbase + kt*32);
      const short8 na = *reinterpret_cast<const short8*>(nbase + kt*32);
      #pragma unroll
      for (int i = 0; i < 2; ++i) {
        const int tau = w + 4*i;
        if (tau < 6) {
          const int isOn = (tau >= 3) ? 1 : 0;
          const int nt2 = tau - 3*isOn;
          acc2b[i] = MFMA(pa, WF[(size_t)((isOn?FW1I:FW1R)  + kt*3 + nt2)*64 + lane], acc2b[i]);
          acc2b[i] = MFMA(na, WF[(size_t)((isOn?FW1R:FW1IN) + kt*3 + nt2)*64 + lane], acc2b[i]);
        }
      }
    }
    if (w >= 2) {
      const u16* pb2 = p2 + (lane & 15)*56 + (lane >> 4)*8;
      const u16* nb2 = n2 + (lane & 15)*56 + (lane >> 4)*8;
      const int isOn2 = (w == 3);
      #pragma unroll
      for (int kt = 0; kt < 2; ++kt) {
        const short8 pa = *reinterpret_cast<const short8*>(pb2 + kt*32);
        const short8 na = *reinterpret_cast<const short8*>(nb2 + kt*32);
        acc2c = MFMA(pa, WF[(size_t)((isOn2?FW2I:FW2R)  + kt)*64 + lane], acc2c);
        acc2c = MFMA(na, WF[(size_t)((isOn2?FW2R:FW2IN) + kt)*64 + lane], acc2c);
      }
    }
  }
  __syncthreads();  // B3: all feature reads done

  // o0 write (aliases m0)
  {
    #pragma unroll
    for (int i = 0; i < 3; ++i) {
      const int nt = w + 4*i;
      if (nt < 10) {
        const int col = nt*16 + (lane & 15);
        const int r0  = (lane >> 4)*4;
        #pragma unroll
        for (int j = 0; j < 4; ++j)
          o0f[(r0+j)*164 + col] = acc2a[i][j] * 0.046423835f;   // 1/sqrt(464)
      }
    }
  }
  __syncthreads();  // B4: o0 ready

  // op1/on1/op2/on2 writes (alias p1/n1/p2/n2) + A1 (silu/gates, reads o0)
  {
    #pragma unroll
    for (int i = 0; i < 2; ++i) {
      const int tau = w + 4*i;
      if (tau < 6) {
        const int isOn = (tau >= 3) ? 1 : 0;
        const int nt2 = tau - 3*isOn;
        float* dst = isOn ? on1f : op1f;
        const int col = nt2*16 + (lane & 15);
        const int r0  = (lane >> 4)*4;
        #pragma unroll
        for (int j = 0; j < 4; ++j)
          dst[(r0+j)*52 + col] = acc2b[i][j] * (1.f/12.f);
      }
    }
    if (w >= 2) {
      float* dst = (w == 3) ? on2f : op2f;
      const int r0 = (lane >> 4)*4;
      #pragma unroll
      for (int j = 0; j < 4; ++j)
        dst[(r0+j)*20 + (lane & 15)] = acc2c[j] * 0.14433757f;  // 1/sqrt(48)
    }
  }
  {
    const int e = t >> 4, l16 = t & 15;
    const float d0 = Dc[e*40];
    #pragma unroll
    for (int k = 0; k < 7; ++k) {
      const int p = l16 + 16*k;
      const float x = o0f[e*164 + p] * d0;
      const float sg = 1.f/(1.f + __expf(-x));
      if (p < 64) scs[e*72 + p] = f2b(x * sg);
      else        gates[e*48 + (p - 64)] = f2b(sg);
    }
  }
  __syncthreads();  // B5

  // A2: rotate-back + gate -> g1/g2 bf16 staging (D coefs from LDS)
  {
    const int e = t >> 4, l16 = t & 15;
    const float* DcE = Dc + e*40;
    #pragma unroll
    for (int k = 0; k < 6; ++k) {
      const int item = l16 + 16*k;            // 0..95
      const int c = item/3, m = item - 3*c;
      const float val = DcE[1 + m]     * on1f[e*52 + c]
                      + DcE[1 + 3 + m] * o0f[e*164 + 112 + c]
                      + DcE[1 + 6 + m] * op1f[e*52 + c];
      const float g = b2f(gates[e*48 + c]);
      g1s[m*640 + e*40 + c] = f2b(val * g);
    }
    const int c = l16;
    const float f0 = on2f[e*20 + c];
    const float f1 = on1f[e*52 + 32 + c];
    const float f2c = o0f[e*164 + 144 + c];
    const float f3 = op1f[e*52 + 32 + c];
    const float f4 = op2f[e*20 + c];
    const float gg = b2f(gates[e*48 + 32 + c]);
    #pragma unroll
    for (int m = 0; m < 5; ++m) {
      const float val = DcE[12 + m]*f0 + DcE[12 + 5 + m]*f1 + DcE[12 + 10 + m]*f2c
                      + DcE[12 + 15 + m]*f3 + DcE[12 + 20 + m]*f4;
      g2s[m*392 + e*24 + c] = f2b(val * gg);
    }
  }
  __syncthreads();  // B6

  // ---- Phase 3: final small matmuls (15 MFMA tasks over 4 waves) + store ----
  for (int tau = w; tau < 15; tau += 4) {
    const int col16 = lane & 15;
    const int r0 = (lane >> 4)*4;
    if (tau < 4) {            // y0: sc[16x64] @ lp_w0
      const int ntt = tau;
      f32x4 a0 = Z4;
      #pragma unroll
      for (int kt = 0; kt < 2; ++kt) {
        const short8 a = *reinterpret_cast<const short8*>(
            scs + (lane & 15)*72 + kt*32 + (lane >> 4)*8);
        a0 = MFMA(a, WF[(size_t)(FL0 + kt*4 + ntt)*64 + lane], a0);
      }
      const int col = ntt*16 + col16;
      const float bias = lp_b0[col];
      #pragma unroll
      for (int j = 0; j < 4; ++j) {
        const int er = eb0 + r0 + j;
        if (er < A) out[(size_t)er*240 + col] = a0[j]*0.125f + bias;
      }
    } else if (tau < 10) {    // y1: g1[m][16x32] @ lp_w1
      const int u = tau - 4, m = u >> 1, ntt = u & 1;
      const short8 a = *reinterpret_cast<const short8*>(
          g1s + m*640 + (lane & 15)*40 + (lane >> 4)*8);
      f32x4 a0 = Z4;
      a0 = MFMA(a, WF[(size_t)(FL1 + ntt)*64 + lane], a0);
      const int d = ntt*16 + col16;
      const int col = 64 + d*3 + m;
      #pragma unroll
      for (int j = 0; j < 4; ++j) {
        const int er = eb0 + r0 + j;
        if (er < A) out[(size_t)er*240 + col] = a0[j]*0.17677670f;  // 1/sqrt(32)
      }
    } else {                  // y2: g2[m][16x32(zero-pad)] @ lp_w2
      const int m = tau - 10;
      const short8 a = *reinterpret_cast<const short8*>(
          g2s + m*392 + (lane & 15)*24 + (lane >> 4)*8);
      f32x4 a0 = Z4;
      a0 = MFMA(a, WF[(size_t)FL2*64 + lane], a0);
      const int col = 160 + col16*5 + m;
      #pragma unroll
      for (int j = 0; j < 4; ++j) {
        const int er = eb0 + r0 + j;
        if (er < A) out[(size_t)er*240 + col] = a0[j]*0.25f;        // 1/sqrt(16)
      }
    }
  }
}

extern "C" void kernel_launch(void* const* d_in, const int* in_sizes, int n_in,
                              void* d_out, int out_size, void* d_ws, size_t ws_size,
                              hipStream_t stream) {
  const float* latents  = (const float*)d_in[0];
  const float* nodef    = (const float*)d_in[1];
  const float* edgef    = (const float*)d_in[2];
  const float* wig      = (const float*)d_in[4];
  const float* ln_n_w0  = (const float*)d_in[5];
  const float* ln_n_b0  = (const float*)d_in[6];
  const float* ln_n_w1  = (const float*)d_in[7];
  const float* ln_n_w2  = (const float*)d_in[8];
  const float* ln_e_w0  = (const float*)d_in[9];
  const float* ln_e_b0  = (const float*)d_in[10];
  const float* ln_e_w1  = (const float*)d_in[11];
  const float* ln_e_w2  = (const float*)d_in[12];
  const float* so2_w0   = (const float*)d_in[13];
  const float* so2_w1r  = (const float*)d_in[14];
  const float* so2_w1i  = (const float*)d_in[15];
  const float* so2_w2r  = (const float*)d_in[16];
  const float* so2_w2i  = (const float*)d_in[17];
  const float* lp_w0    = (const float*)d_in[18];
  const float* lp_b0    = (const float*)d_in[19];
  const float* lp_w1    = (const float*)d_in[20];
  const float* lp_w2    = (const float*)d_in[21];
  const int*   edge_index   = (const int*)d_in[22];
  const int*   active_edges = (const int*)d_in[23];

  const int Etot = in_sizes[2] / 240;
  const int N    = in_sizes[1] / 240;
  const int A    = in_sizes[23];

  u16* ws  = (u16*)d_ws;                 // WF table: NFRAG*1024 B
  u16* nls = ws + WS_NLS_OFF;            // node-LN table: N*640 B

  const int pthreads = NFRAG * 64;
  hipLaunchKernelGGL(prep_w, dim3((pthreads + 255) / 256), dim3(256), 0, stream,
                     so2_w0, so2_w1r, so2_w1i, so2_w2r, so2_w2i,
                     lp_w0, lp_w1, lp_w2, ws);

  hipLaunchKernelGGL(ln_nodes, dim3((N + 3) / 4), dim3(256), 0, stream,
                     nodef, ln_n_w0, ln_n_b0, ln_n_w1, ln_n_w2, nls, N);

  const int grid = (A + EB - 1) / EB;
  hipLaunchKernelGGL(iel_mfma, dim3(grid), dim3(NT), 0, stream,
                     latents, edgef, wig,
                     ln_e_w0, ln_e_b0, ln_e_w1, ln_e_w2,
                     lp_b0, edge_index, active_edges, ws, nls,
                     (float*)d_out, Etot, A);
}